// Round 1
// baseline (1907.356 us; speedup 1.0000x reference)
//
#include <hip/hip_runtime.h>
#include <math.h>

#define N_NODES 50000
#define N_EDGES 800000
#define IN_CH 512
#define HID_CH 512
#define OUT_CH 256

// ---------------- degree / CSR build ----------------

__global__ void zero_int_kernel(int* __restrict__ p, int n) {
    int i = blockIdx.x * blockDim.x + threadIdx.x;
    if (i < n) p[i] = 0;
}

__global__ void count_deg_kernel(const int* __restrict__ dst, int* __restrict__ deg) {
    int e = blockIdx.x * blockDim.x + threadIdx.x;
    if (e < N_EDGES) atomicAdd(&deg[dst[e]], 1);
}

__global__ void dinv_kernel(const int* __restrict__ deg, float* __restrict__ dinv) {
    int i = blockIdx.x * blockDim.x + threadIdx.x;
    if (i < N_NODES) dinv[i] = rsqrtf((float)deg[i] + 1.0f);  // +1 for self-loop
}

// Single-block chunked inclusive scan -> exclusive offsets + cursor copy.
__global__ __launch_bounds__(1024) void scan_kernel(const int* __restrict__ deg,
                                                    int* __restrict__ offsets,
                                                    int* __restrict__ cursor) {
    __shared__ int sm[1024];
    int t = threadIdx.x;
    int base = 0;
    if (t == 0) offsets[0] = 0;
    for (int start = 0; start < N_NODES; start += 1024) {
        int i = start + t;
        int v = (i < N_NODES) ? deg[i] : 0;
        sm[t] = v;
        __syncthreads();
        // Hillis-Steele inclusive scan
        for (int off = 1; off < 1024; off <<= 1) {
            int x = (t >= off) ? sm[t - off] : 0;
            __syncthreads();
            sm[t] += x;
            __syncthreads();
        }
        if (i < N_NODES) {
            offsets[i + 1] = base + sm[t];
            cursor[i] = base + sm[t] - v;  // exclusive prefix = row start
        }
        base += sm[1023];
        __syncthreads();  // protect sm[1023] read before next-chunk overwrite
    }
}

__global__ void fill_csr_kernel(const int* __restrict__ src, const int* __restrict__ dst,
                                int* __restrict__ cursor, int* __restrict__ csr_src,
                                float* __restrict__ csr_w, const float* __restrict__ dinv) {
    int e = blockIdx.x * blockDim.x + threadIdx.x;
    if (e < N_EDGES) {
        int s = src[e], d = dst[e];
        int p = atomicAdd(&cursor[d], 1);
        csr_src[p] = s;
        csr_w[p] = dinv[s] * dinv[d];
    }
}

// ---------------- fp32 tiled GEMM: C[MxN] = A[MxK] @ B[KxN] ----------------

#define BM 64
#define BN 64
#define BK 16

__global__ __launch_bounds__(256) void gemm_kernel(const float* __restrict__ A,
                                                   const float* __restrict__ B,
                                                   float* __restrict__ C,
                                                   int M, int N, int K) {
    __shared__ float As[BK][BM + 4];  // row stride 68 floats = 272B (16B-aligned)
    __shared__ float Bs[BK][BN + 4];

    int t = threadIdx.x;
    int row0 = blockIdx.x * BM;
    int col0 = blockIdx.y * BN;
    int tm = t >> 4, tn = t & 15;  // 16x16 thread grid, each computes 4x4

    // A tile load: thread -> one float4; 64 rows x 16 cols
    int ar = t >> 2, ac = (t & 3) * 4;
    // B tile load: 16 rows x 64 cols
    int br = t >> 4, bc = (t & 15) * 4;

    bool arow_ok = (row0 + ar) < M;
    const float* Aptr = A + (size_t)(row0 + ar) * K + ac;

    float acc[4][4] = {};

    for (int k0 = 0; k0 < K; k0 += BK) {
        float4 av = make_float4(0.f, 0.f, 0.f, 0.f);
        if (arow_ok) av = *(const float4*)(Aptr + k0);
        float4 bv = *(const float4*)(B + (size_t)(k0 + br) * N + col0 + bc);

        __syncthreads();  // previous compute done before overwriting LDS
        As[ac + 0][ar] = av.x;
        As[ac + 1][ar] = av.y;
        As[ac + 2][ar] = av.z;
        As[ac + 3][ar] = av.w;
        *(float4*)&Bs[br][bc] = bv;
        __syncthreads();

#pragma unroll
        for (int k = 0; k < BK; k++) {
            float4 a = *(const float4*)&As[k][tm * 4];
            float4 b = *(const float4*)&Bs[k][tn * 4];
            acc[0][0] += a.x * b.x; acc[0][1] += a.x * b.y; acc[0][2] += a.x * b.z; acc[0][3] += a.x * b.w;
            acc[1][0] += a.y * b.x; acc[1][1] += a.y * b.y; acc[1][2] += a.y * b.z; acc[1][3] += a.y * b.w;
            acc[2][0] += a.z * b.x; acc[2][1] += a.z * b.y; acc[2][2] += a.z * b.z; acc[2][3] += a.z * b.w;
            acc[3][0] += a.w * b.x; acc[3][1] += a.w * b.y; acc[3][2] += a.w * b.z; acc[3][3] += a.w * b.w;
        }
    }

#pragma unroll
    for (int i = 0; i < 4; i++) {
        int row = row0 + tm * 4 + i;
        if (row < M) {
            float4 v = make_float4(acc[i][0], acc[i][1], acc[i][2], acc[i][3]);
            *(float4*)(C + (size_t)row * N + col0 + tn * 4) = v;
        }
    }
}

// ---------------- aggregation: out[i] = sum_{e:dst=i} w_e * h[src_e] + dinv_i^2 * h[i] + b ----------------

__device__ __forceinline__ float gelu_tanh(float x) {
    // jax.nn.gelu default: approximate=True (tanh form)
    float x3 = x * x * x;
    float inner = 0.7978845608028654f * (x + 0.044715f * x3);
    return 0.5f * x * (1.0f + tanhf(inner));
}

template <int C, int GELU>
__global__ __launch_bounds__(C / 2) void aggregate_kernel(const float* __restrict__ h,
                                                          const int* __restrict__ offsets,
                                                          const int* __restrict__ csr_src,
                                                          const float* __restrict__ csr_w,
                                                          const float* __restrict__ dinv,
                                                          const float* __restrict__ bias,
                                                          float* __restrict__ out) {
    int node = blockIdx.x;
    int t = threadIdx.x;  // C/2 threads, each handles float2
    int ch = t * 2;

    int p0 = offsets[node], p1 = offsets[node + 1];
    float accx = 0.f, accy = 0.f;
    for (int p = p0; p < p1; p++) {
        int s = csr_src[p];
        float w = csr_w[p];
        float2 hv = *(const float2*)(h + (size_t)s * C + ch);
        accx += w * hv.x;
        accy += w * hv.y;
    }
    float di = dinv[node];
    float wself = di * di;
    float2 hs = *(const float2*)(h + (size_t)node * C + ch);
    accx += wself * hs.x + bias[ch];
    accy += wself * hs.y + bias[ch + 1];
    if (GELU) {
        accx = gelu_tanh(accx);
        accy = gelu_tanh(accy);
    }
    float2 o = make_float2(accx, accy);
    *(float2*)(out + (size_t)node * C + ch) = o;
}

// ---------------- launch ----------------

extern "C" void kernel_launch(void* const* d_in, const int* in_sizes, int n_in,
                              void* d_out, int out_size, void* d_ws, size_t ws_size,
                              hipStream_t stream) {
    const float* x   = (const float*)d_in[0];
    const int* eidx  = (const int*)d_in[1];
    const float* W1  = (const float*)d_in[2];
    const float* b1  = (const float*)d_in[3];
    const float* W2  = (const float*)d_in[4];
    const float* b2  = (const float*)d_in[5];
    const float* W3  = (const float*)d_in[6];
    const float* b3  = (const float*)d_in[7];
    float* out = (float*)d_out;

    const int* src = eidx;            // edge_index[0,:]
    const int* dst = eidx + N_EDGES;  // edge_index[1,:]

    // workspace carve-up
    char* ws = (char*)d_ws;
    float* bufA = (float*)ws;                       ws += (size_t)N_NODES * 512 * sizeof(float);
    float* bufB = (float*)ws;                       ws += (size_t)N_NODES * 512 * sizeof(float);
    int*   deg     = (int*)ws;                      ws += (size_t)N_NODES * sizeof(int);
    float* dinv    = (float*)ws;                    ws += (size_t)N_NODES * sizeof(float);
    int*   offsets = (int*)ws;                      ws += (size_t)(N_NODES + 1) * sizeof(int);
    int*   cursor  = (int*)ws;                      ws += (size_t)N_NODES * sizeof(int);
    int*   csr_src = (int*)ws;                      ws += (size_t)N_EDGES * sizeof(int);
    float* csr_w   = (float*)ws;                    ws += (size_t)N_EDGES * sizeof(float);

    // ---- CSR build ----
    zero_int_kernel<<<(N_NODES + 255) / 256, 256, 0, stream>>>(deg, N_NODES);
    count_deg_kernel<<<(N_EDGES + 255) / 256, 256, 0, stream>>>(dst, deg);
    dinv_kernel<<<(N_NODES + 255) / 256, 256, 0, stream>>>(deg, dinv);
    scan_kernel<<<1, 1024, 0, stream>>>(deg, offsets, cursor);
    fill_csr_kernel<<<(N_EDGES + 255) / 256, 256, 0, stream>>>(src, dst, cursor, csr_src, csr_w, dinv);

    dim3 blk(256);

    // ---- layer 1: h = x @ W1 ; agg + b1 + gelu ----
    {
        dim3 grid((N_NODES + BM - 1) / BM, HID_CH / BN);
        gemm_kernel<<<grid, blk, 0, stream>>>(x, W1, bufA, N_NODES, HID_CH, IN_CH);
        aggregate_kernel<512, 1><<<N_NODES, 256, 0, stream>>>(bufA, offsets, csr_src, csr_w, dinv, b1, bufB);
    }
    // ---- layer 2 ----
    {
        dim3 grid((N_NODES + BM - 1) / BM, HID_CH / BN);
        gemm_kernel<<<grid, blk, 0, stream>>>(bufB, W2, bufA, N_NODES, HID_CH, HID_CH);
        aggregate_kernel<512, 1><<<N_NODES, 256, 0, stream>>>(bufA, offsets, csr_src, csr_w, dinv, b2, bufB);
    }
    // ---- layer 3 (no gelu) ----
    {
        dim3 grid((N_NODES + BM - 1) / BM, OUT_CH / BN);
        gemm_kernel<<<grid, blk, 0, stream>>>(bufB, W3, bufA, N_NODES, OUT_CH, HID_CH);
        aggregate_kernel<256, 0><<<N_NODES, 128, 0, stream>>>(bufA, offsets, csr_src, csr_w, dinv, b3, out);
    }
}

// Round 2
// 1343.288 us; speedup vs baseline: 1.4199x; 1.4199x over previous
//
#include <hip/hip_runtime.h>
#include <math.h>

#define N_NODES 50000
#define N_EDGES 800000
#define MPAD 50048            // 391 * 128, so GEMM needs no M bounds checks
#define KPHYS 1024            // A2 physical row width: [hi(512) | lo(512)]
#define KVIRT 1536            // virtual K: hi*hi + lo*hi + hi*lo

// ---------------- bf16 helpers ----------------

__device__ __forceinline__ unsigned short bf16_rn(float f) {
    unsigned u = __float_as_uint(f);
    u += 0x7FFFu + ((u >> 16) & 1u);  // round-to-nearest-even
    return (unsigned short)(u >> 16);
}
__device__ __forceinline__ float bf16_f32(unsigned short h) {
    return __uint_as_float(((unsigned)h) << 16);
}

// ---------------- degree / CSR build ----------------

__global__ void zero_int_kernel(int* __restrict__ p, int n) {
    int i = blockIdx.x * blockDim.x + threadIdx.x;
    if (i < n) p[i] = 0;
}

__global__ void count_deg_kernel(const int* __restrict__ dst, int* __restrict__ deg) {
    int e = blockIdx.x * blockDim.x + threadIdx.x;
    if (e < N_EDGES) atomicAdd(&deg[dst[e]], 1);
}

__global__ void dinv_kernel(const int* __restrict__ deg, float* __restrict__ dinv) {
    int i = blockIdx.x * blockDim.x + threadIdx.x;
    if (i < N_NODES) dinv[i] = rsqrtf((float)deg[i] + 1.0f);  // +1 self-loop
}

__global__ __launch_bounds__(1024) void scan_kernel(const int* __restrict__ deg,
                                                    int* __restrict__ offsets,
                                                    int* __restrict__ cursor) {
    __shared__ int sm[1024];
    int t = threadIdx.x;
    int base = 0;
    if (t == 0) offsets[0] = 0;
    for (int start = 0; start < N_NODES; start += 1024) {
        int i = start + t;
        int v = (i < N_NODES) ? deg[i] : 0;
        sm[t] = v;
        __syncthreads();
        for (int off = 1; off < 1024; off <<= 1) {
            int x = (t >= off) ? sm[t - off] : 0;
            __syncthreads();
            sm[t] += x;
            __syncthreads();
        }
        if (i < N_NODES) {
            offsets[i + 1] = base + sm[t];
            cursor[i] = base + sm[t] - v;
        }
        base += sm[1023];
        __syncthreads();
    }
}

__global__ void fill_csr_kernel(const int* __restrict__ src, const int* __restrict__ dst,
                                int* __restrict__ cursor, int* __restrict__ csr_src,
                                float* __restrict__ csr_w, const float* __restrict__ dinv) {
    int e = blockIdx.x * blockDim.x + threadIdx.x;
    if (e < N_EDGES) {
        int s = src[e], d = dst[e];
        int p = atomicAdd(&cursor[d], 1);
        csr_src[p] = s;
        csr_w[p] = dinv[s] * dinv[d];
    }
}

// ---------------- split-bf16 MFMA GEMM ----------------
// C[MPAD x N] = A2(virtual [MPAD x KVIRT]) * B2T^T, B2T is [N x KVIRT] (B^T layout).
// A2 physical [MPAD x KPHYS] = [hi | lo]; virtual k>=1024 wraps to hi block.

typedef __attribute__((ext_vector_type(8))) short bf16x8;
typedef __attribute__((ext_vector_type(4))) float floatx4;

#define GLL16(g, l)                                                                   \
    __builtin_amdgcn_global_load_lds((__attribute__((address_space(1))) const void*)(g), \
                                     (__attribute__((address_space(3))) void*)(l), 16, 0, 0)

__global__ __launch_bounds__(256) void gemm_split_bt(const unsigned short* __restrict__ A2,
                                                     const unsigned short* __restrict__ B2T,
                                                     float* __restrict__ C, int N) {
    __shared__ unsigned short As[128 * 32];  // [m][k], k contiguous
    __shared__ unsigned short Bs[128 * 32];  // [n][k], k contiguous

    const int t = threadIdx.x;
    const int lane = t & 63;
    const int quad = lane >> 4;
    const int l15 = lane & 15;
    const int w = t >> 6;
    const int wm = w & 1, wn = w >> 1;
    const int row0 = blockIdx.x * 128;
    const int col0 = blockIdx.y * 128;

    floatx4 acc[4][4];
#pragma unroll
    for (int i = 0; i < 4; i++)
#pragma unroll
        for (int j = 0; j < 4; j++) acc[i][j] = (floatx4){0.f, 0.f, 0.f, 0.f};

    // staging: chunk c=t -> row c>>2, k-offset (c&3)*8; LDS byte = c*16 (lane-contiguous per wave)
    const int sr = t >> 2;
    const int sk = (t & 3) * 8;
    const unsigned short* Arow0 = A2 + (size_t)(row0 + sr) * KPHYS + sk;
    const unsigned short* Arow1 = Arow0 + (size_t)64 * KPHYS;
    const unsigned short* Brow0 = B2T + (size_t)(col0 + sr) * KVIRT + sk;
    const unsigned short* Brow1 = Brow0 + (size_t)64 * KVIRT;
    unsigned short* lA0 = As + t * 8;
    unsigned short* lA1 = As + 2048 + t * 8;
    unsigned short* lB0 = Bs + t * 8;
    unsigned short* lB1 = Bs + 2048 + t * 8;

    for (int kb = 0; kb < KVIRT; kb += 32) {
        const int kA = (kb < KPHYS) ? kb : kb - KPHYS;  // wrap virtual hi-replay onto physical hi
        __syncthreads();
        GLL16(Arow0 + kA, lA0);
        GLL16(Arow1 + kA, lA1);
        GLL16(Brow0 + kb, lB0);
        GLL16(Brow1 + kb, lB1);
        __syncthreads();

        bf16x8 af[4], bf[4];
#pragma unroll
        for (int mt = 0; mt < 4; mt++)
            af[mt] = *(const bf16x8*)(As + (wm * 64 + mt * 16 + l15) * 32 + quad * 8);
#pragma unroll
        for (int nt = 0; nt < 4; nt++)
            bf[nt] = *(const bf16x8*)(Bs + (wn * 64 + nt * 16 + l15) * 32 + quad * 8);
#pragma unroll
        for (int mt = 0; mt < 4; mt++)
#pragma unroll
            for (int nt = 0; nt < 4; nt++)
                acc[mt][nt] = __builtin_amdgcn_mfma_f32_16x16x32_bf16(af[mt], bf[nt], acc[mt][nt], 0, 0, 0);
    }

    // epilogue: C/D layout col = lane&15, row = quad*4 + reg
#pragma unroll
    for (int mt = 0; mt < 4; mt++) {
#pragma unroll
        for (int r = 0; r < 4; r++) {
            int row = row0 + wm * 64 + mt * 16 + quad * 4 + r;
            float* Cp = C + (size_t)row * N + col0 + wn * 64 + l15;
#pragma unroll
            for (int nt = 0; nt < 4; nt++) Cp[nt * 16] = acc[mt][nt][r];
        }
    }
}

// ---------------- weight split (W [K x N] fp32 -> B2T [N x KVIRT] bf16) ----------------
// B2T[n][k]      = hi(W[k][n])   (matches A hi)
// B2T[n][512+k]  = hi(W[k][n])   (matches A lo)
// B2T[n][1024+k] = lo(W[k][n])   (matches A hi replay)

__global__ void wsplit_kernel(const float* __restrict__ W, unsigned short* __restrict__ B2T, int N) {
    int idx = blockIdx.x * blockDim.x + threadIdx.x;
    if (idx >= 512 * N) return;
    int k = idx / N, n = idx % N;
    float v = W[(size_t)k * N + n];
    unsigned short hi = bf16_rn(v);
    unsigned short lo = bf16_rn(v - bf16_f32(hi));
    unsigned short* row = B2T + (size_t)n * KVIRT;
    row[k] = hi;
    row[512 + k] = hi;
    row[1024 + k] = lo;
}

// ---------------- x split (fp32 [N_NODES x 512] -> A2 [MPAD x KPHYS]) ----------------

__global__ __launch_bounds__(256) void split_x_kernel(const float* __restrict__ x,
                                                      unsigned short* __restrict__ A2) {
    int m = blockIdx.x;
    int ch = threadIdx.x * 2;
    unsigned short* arow = A2 + (size_t)m * KPHYS;
    float vx = 0.f, vy = 0.f;
    if (m < N_NODES) {
        float2 v = *(const float2*)(x + (size_t)m * 512 + ch);
        vx = v.x;
        vy = v.y;
    }
    unsigned short hx = bf16_rn(vx), hy = bf16_rn(vy);
    arow[ch] = hx;
    arow[ch + 1] = hy;
    arow[512 + ch] = bf16_rn(vx - bf16_f32(hx));
    arow[512 + ch + 1] = bf16_rn(vy - bf16_f32(hy));
}

// ---------------- aggregation ----------------

__device__ __forceinline__ float gelu_tanh(float x) {
    float x3 = x * x * x;
    float inner = 0.7978845608028654f * (x + 0.044715f * x3);
    return 0.5f * x * (1.0f + tanhf(inner));
}

// agg + bias + gelu, output split-bf16 into A2 (feeds next GEMM). h stride = 512.
__global__ __launch_bounds__(256) void aggregate_split_kernel(
    const float* __restrict__ h, const int* __restrict__ offsets, const int* __restrict__ csr_src,
    const float* __restrict__ csr_w, const float* __restrict__ dinv, const float* __restrict__ bias,
    unsigned short* __restrict__ A2) {
    int node = blockIdx.x;
    int ch = threadIdx.x * 2;
    unsigned short* arow = A2 + (size_t)node * KPHYS;
    if (node >= N_NODES) {  // zero pad rows
        arow[ch] = 0; arow[ch + 1] = 0;
        arow[512 + ch] = 0; arow[512 + ch + 1] = 0;
        return;
    }
    int p0 = offsets[node], p1 = offsets[node + 1];
    float accx = 0.f, accy = 0.f;
    for (int p = p0; p < p1; p++) {
        int s = csr_src[p];
        float wgt = csr_w[p];
        float2 hv = *(const float2*)(h + (size_t)s * 512 + ch);
        accx += wgt * hv.x;
        accy += wgt * hv.y;
    }
    float di = dinv[node];
    float wself = di * di;
    float2 hs = *(const float2*)(h + (size_t)node * 512 + ch);
    accx += wself * hs.x + bias[ch];
    accy += wself * hs.y + bias[ch + 1];
    accx = gelu_tanh(accx);
    accy = gelu_tanh(accy);
    unsigned short hx = bf16_rn(accx), hy = bf16_rn(accy);
    arow[ch] = hx;
    arow[ch + 1] = hy;
    arow[512 + ch] = bf16_rn(accx - bf16_f32(hx));
    arow[512 + ch + 1] = bf16_rn(accy - bf16_f32(hy));
}

// final agg: fp32 out, C channels = 256, no gelu
__global__ __launch_bounds__(128) void aggregate_final_kernel(
    const float* __restrict__ h, const int* __restrict__ offsets, const int* __restrict__ csr_src,
    const float* __restrict__ csr_w, const float* __restrict__ dinv, const float* __restrict__ bias,
    float* __restrict__ out) {
    int node = blockIdx.x;
    int ch = threadIdx.x * 2;
    int p0 = offsets[node], p1 = offsets[node + 1];
    float accx = 0.f, accy = 0.f;
    for (int p = p0; p < p1; p++) {
        int s = csr_src[p];
        float wgt = csr_w[p];
        float2 hv = *(const float2*)(h + (size_t)s * 256 + ch);
        accx += wgt * hv.x;
        accy += wgt * hv.y;
    }
    float di = dinv[node];
    float wself = di * di;
    float2 hs = *(const float2*)(h + (size_t)node * 256 + ch);
    accx += wself * hs.x + bias[ch];
    accy += wself * hs.y + bias[ch + 1];
    *(float2*)(out + (size_t)node * 256 + ch) = make_float2(accx, accy);
}

// ---------------- launch ----------------

static inline char* align16(char* p) { return (char*)(((size_t)p + 15) & ~(size_t)15); }

extern "C" void kernel_launch(void* const* d_in, const int* in_sizes, int n_in,
                              void* d_out, int out_size, void* d_ws, size_t ws_size,
                              hipStream_t stream) {
    const float* x  = (const float*)d_in[0];
    const int* eidx = (const int*)d_in[1];
    const float* W1 = (const float*)d_in[2];
    const float* b1 = (const float*)d_in[3];
    const float* W2 = (const float*)d_in[4];
    const float* b2 = (const float*)d_in[5];
    const float* W3 = (const float*)d_in[6];
    const float* b3 = (const float*)d_in[7];
    float* out = (float*)d_out;

    const int* src = eidx;
    const int* dst = eidx + N_EDGES;

    char* ws = (char*)d_ws;
    unsigned short* A2 = (unsigned short*)ws;  ws += (size_t)MPAD * KPHYS * 2;       // 102.5 MB
    float* Cbuf = (float*)ws;                  ws += (size_t)MPAD * 512 * 4;          // 102.5 MB
    unsigned short* B2T1 = (unsigned short*)ws; ws += (size_t)512 * KVIRT * 2;
    unsigned short* B2T2 = (unsigned short*)ws; ws += (size_t)512 * KVIRT * 2;
    unsigned short* B2T3 = (unsigned short*)ws; ws += (size_t)256 * KVIRT * 2;
    int* deg = (int*)ws;        ws = align16(ws + (size_t)N_NODES * 4);
    float* dinv = (float*)ws;   ws = align16(ws + (size_t)N_NODES * 4);
    int* offsets = (int*)ws;    ws = align16(ws + (size_t)(N_NODES + 1) * 4);
    int* cursor = (int*)ws;     ws = align16(ws + (size_t)N_NODES * 4);
    int* csr_src = (int*)ws;    ws = align16(ws + (size_t)N_EDGES * 4);
    float* csr_w = (float*)ws;  ws = align16(ws + (size_t)N_EDGES * 4);

    // ---- CSR build ----
    zero_int_kernel<<<(N_NODES + 255) / 256, 256, 0, stream>>>(deg, N_NODES);
    count_deg_kernel<<<(N_EDGES + 255) / 256, 256, 0, stream>>>(dst, deg);
    dinv_kernel<<<(N_NODES + 255) / 256, 256, 0, stream>>>(deg, dinv);
    scan_kernel<<<1, 1024, 0, stream>>>(deg, offsets, cursor);
    fill_csr_kernel<<<(N_EDGES + 255) / 256, 256, 0, stream>>>(src, dst, cursor, csr_src, csr_w, dinv);

    // ---- weight + input splits ----
    wsplit_kernel<<<(512 * 512 + 255) / 256, 256, 0, stream>>>(W1, B2T1, 512);
    wsplit_kernel<<<(512 * 512 + 255) / 256, 256, 0, stream>>>(W2, B2T2, 512);
    wsplit_kernel<<<(512 * 256 + 255) / 256, 256, 0, stream>>>(W3, B2T3, 256);
    split_x_kernel<<<MPAD, 256, 0, stream>>>(x, A2);

    // ---- layer 1 ----
    {
        dim3 grid(MPAD / 128, 512 / 128);
        gemm_split_bt<<<grid, 256, 0, stream>>>(A2, B2T1, Cbuf, 512);
        aggregate_split_kernel<<<MPAD, 256, 0, stream>>>(Cbuf, offsets, csr_src, csr_w, dinv, b1, A2);
    }
    // ---- layer 2 ----
    {
        dim3 grid(MPAD / 128, 512 / 128);
        gemm_split_bt<<<grid, 256, 0, stream>>>(A2, B2T2, Cbuf, 512);
        aggregate_split_kernel<<<MPAD, 256, 0, stream>>>(Cbuf, offsets, csr_src, csr_w, dinv, b2, A2);
    }
    // ---- layer 3 ----
    {
        dim3 grid(MPAD / 128, 256 / 128);
        gemm_split_bt<<<grid, 256, 0, stream>>>(A2, B2T3, Cbuf, 256);
        aggregate_final_kernel<<<N_NODES, 128, 0, stream>>>(Cbuf, offsets, csr_src, csr_w, dinv, b3, out);
    }
}